// Round 6
// baseline (213.888 us; speedup 1.0000x reference)
//
#include <hip/hip_runtime.h>
#include <math.h>

// SGC: K=2 hops of D^-1/2 (A+I) D^-1/2, then x@W+b, then log_softmax.
// N=100000, D=64, C=40, E=1600000.
//
// R14 (this round): concurrency on all three axes at once.
//  - 4 rows/wave, 16-lane x uint2 gathers (R12 geometry, 2x R13's waves) but
//    with R13's unconditional loads + guard + sched_barrier(0): u-payload is
//    32 VGPR so all 16 gathers can be live. Accumulates stay predicated.
//  - pinfo[pidx] = {csr_start, padded_len, row, dis} (uint4, written by
//    build_csr at perm time): ONE load replaces the serial perm -> row_info
//    -> dis chain (2 fewer dependent round-trips per wave).
//  - cv double-buffer: next iteration's 4 csr uint4 loads issue alongside the
//    current iteration's 16 gathers (guard makes the overrun safe) -> one
//    memory phase per iteration in steady state.
//  - __launch_bounds__(256,5): VGPR cap ~102, 20 waves/CU.
//
// Carried: guard region (R13), fused sort+scale (R13), bitonic row sort
// (R11), degree-grouped scheduling (R9), pk_add accumulate, LDS-transpose
// GEMV epilogue (R9/R12).

#define D_FEAT 64
#define NCLS 40
#define BROWS 512       // rows per bucket
#define BROWS_LOG 9
#define BINCAP 10240    // per-bucket edge capacity (mean 8192, sd ~90)
#define CSRCAP 12288    // per-bucket csr capacity (max padded 11776 + 512 guard)
#define EPT 25          // edges per thread in bin_edges (250 blocks)

typedef float v2f __attribute__((ext_vector_type(2)));

__device__ __forceinline__ unsigned pack_bf16_2(float lo, float hi) {
    unsigned ulo = __float_as_uint(lo);
    unsigned uhi = __float_as_uint(hi);
    ulo = (ulo + 0x7fffu + ((ulo >> 16) & 1u)) >> 16;           // RNE
    uhi = (uhi + 0x7fffu + ((uhi >> 16) & 1u)) & 0xffff0000u;   // RNE
    return uhi | ulo;
}

// packed-accumulate one dword (2 bf16 features) into a float2 accumulator
__device__ __forceinline__ void acc2p(unsigned u, v2f& a) {
    v2f v;
    v.x = __uint_as_float(u << 16);
    v.y = __uint_as_float(u & 0xffff0000u);
    a += v;   // <2 x float> fadd -> v_pk_add_f32
}

// Bin edges into per-bucket regions. Packed entry: (row&511)<<17 | col.
// (Requires n <= 131072 so col fits 17 bits; n = 100000 here.)
__global__ __launch_bounds__(256) void bin_edges_kernel(const int* __restrict__ rows,
                                                        const int* __restrict__ cols,
                                                        int* __restrict__ bucket_cursor,
                                                        unsigned* __restrict__ bins,
                                                        int e, int nb) {
    __shared__ int cnt[512];
    for (int i = threadIdx.x; i < nb; i += 256) cnt[i] = 0;
    __syncthreads();
    int base = blockIdx.x * (256 * EPT) + threadIdx.x;
    int rr[EPT], cc[EPT];
#pragma unroll
    for (int k = 0; k < EPT; k++) {
        int idx = base + k * 256;
        if (idx < e) { rr[k] = rows[idx]; cc[k] = cols[idx]; }
        else { rr[k] = -1; cc[k] = 0; }
    }
#pragma unroll
    for (int k = 0; k < EPT; k++)
        if (rr[k] >= 0) atomicAdd(&cnt[rr[k] >> BROWS_LOG], 1);
    __syncthreads();
    for (int i = threadIdx.x; i < nb; i += 256) {
        int c = cnt[i];
        cnt[i] = (c > 0) ? atomicAdd(&bucket_cursor[i], c) : 0;  // global base
    }
    __syncthreads();
#pragma unroll
    for (int k = 0; k < EPT; k++) {
        if (rr[k] >= 0) {
            int b = rr[k] >> BROWS_LOG;
            int pos = atomicAdd(&cnt[b], 1);  // absolute pos within bucket
            bins[(size_t)b * BINCAP + pos] =
                ((unsigned)(rr[k] & (BROWS - 1)) << 17) | (unsigned)cc[k];
        }
    }
}

// One 512-thread block per bucket, all staged in LDS. Emits UNSORTED,
// dummy-padded CSR + 512-entry guard (value n) + row_info + dis + pinfo
// (degree-grouped wave schedule, packed with csr base/len/row/dis).
__global__ __launch_bounds__(512) void build_csr_kernel(const unsigned* __restrict__ bins,
                                                        const int* __restrict__ bucket_cursor,
                                                        int* __restrict__ csr_col,
                                                        uint2* __restrict__ row_info,
                                                        float* __restrict__ dis,
                                                        uint4* __restrict__ pinfo, int n) {
    __shared__ int cnt[512];
    __shared__ int sm[512];
    __shared__ int cur[512];
    __shared__ int lcsr[CSRCAP];  // 48 KB; total static LDS = 54 KB
    int b = blockIdx.x;
    int tid = threadIdx.x;
    int m = bucket_cursor[b];
    cnt[tid] = 0;
    __syncthreads();
    const unsigned* bp = bins + (size_t)b * BINCAP;
    for (int i = tid; i < m; i += 512) atomicAdd(&cnt[bp[i] >> 17], 1);
    __syncthreads();
    int c = cnt[tid];
    int padded = (c + 3) & ~3;
    int r = b * BROWS + tid;
    float dv = rsqrtf(1.0f + (float)c);
    if (r < n) dis[r] = dv;
    sm[tid] = padded;
    __syncthreads();
    for (int off = 1; off < 512; off <<= 1) {
        int t = (tid >= off) ? sm[tid - off] : 0;
        __syncthreads();
        sm[tid] += t;
        __syncthreads();
    }
    int off0 = sm[tid] - padded;  // exclusive scan
    cur[tid] = off0;
    if (r < n) row_info[r] = make_uint2((unsigned)(b * CSRCAP + off0), (unsigned)padded);
    __syncthreads();
    for (int i = tid; i < m; i += 512) {
        unsigned u = bp[i];
        int pos = atomicAdd(&cur[u >> 17], 1);
        lcsr[pos] = (int)(u & 0x1FFFFu);
    }
    __syncthreads();
    // dummy-pad own row's tail (pad slots gather zero row n in SpMM)
    if (r < n) {
        for (int j = c; j < padded; j++) lcsr[off0 + j] = n;
    }
    __syncthreads();
    int tot = sm[511];  // total padded slots (multiple of 4)
    int4* cp4 = (int4*)(csr_col + (size_t)b * CSRCAP);
    const int4* l4 = (const int4*)lcsr;
    for (int i = tid; i < (tot >> 2); i += 512) cp4[i] = l4[i];
    // guard region: SpMM reads csr (incl. cv prefetch) up to ~80 ints past a
    // row's end; fill 512 entries of value n past tot (row n of xs is zeros).
    {
        int g = tot + tid;
        if (g < CSRCAP) csr_col[(size_t)b * CSRCAP + g] = n;
    }

    // ---- degree-grouped pinfo: counting sort of bucket rows by padded len --
    // (rank order within a bin is nondeterministic, but output is per-row
    //  independent of wave assignment -> bit-identical results.)
    __syncthreads();
    if (tid < 64) cnt[tid] = 0;
    __syncthreads();
    int bin = min(padded >> 2, 63);
    if (r < n) atomicAdd(&cnt[bin], 1);
    __syncthreads();
    if (tid < 64) sm[tid] = cnt[tid];
    __syncthreads();
    for (int off = 1; off < 64; off <<= 1) {
        int t = (tid >= off && tid < 64) ? sm[tid - off] : 0;
        __syncthreads();
        if (tid < 64) sm[tid] += t;
        __syncthreads();
    }
    if (tid < 64) cur[tid] = sm[tid] - cnt[tid];  // exclusive bin base
    __syncthreads();
    if (r < n) {
        int rank = atomicAdd(&cur[bin], 1);
        pinfo[b * BROWS + rank] = make_uint4((unsigned)(b * CSRCAP + off0),
                                             (unsigned)padded, (unsigned)r,
                                             __float_as_uint(dv));
    } else {
        // tid >= valid-count exactly when r >= n
        pinfo[b * BROWS + tid] = make_uint4(0u, 0u, 0xFFFFFFFFu, 0u);
    }
}

// Fused: [0, sortBlocks) = bitonic per-row sort of csr_col (canonical multiset
// order -> bit-identical output); [sortBlocks, ...) = scale_x.
__global__ __launch_bounds__(256) void sort_scale_kernel(int* __restrict__ csr_col,
                                                         const uint2* __restrict__ row_info,
                                                         const float* __restrict__ x,
                                                         const float* __restrict__ dis,
                                                         unsigned* __restrict__ xs0,
                                                         unsigned* __restrict__ xs1,
                                                         int n, int sortBlocks) {
    if ((int)blockIdx.x >= sortBlocks) {
        // ---- scale_x part: xs0[i] = bf16(dis*x), zero dummy row n ----
        int i = ((int)blockIdx.x - sortBlocks) * 256 + threadIdx.x;
        int total = (n + 1) * (D_FEAT / 2);
        if (i >= total) return;
        int node = i >> 5;
        if (node < n) {
            float s = dis[node];
            float2 v = ((const float2*)x)[i];
            xs0[i] = pack_bf16_2(s * v.x, s * v.y);
        } else {
            xs0[i] = 0u;
            xs1[i] = 0u;  // dummy row of hop-1 output
        }
        return;
    }
    // ---- sort part: one half-wave per row ----
    int wid = ((int)blockIdx.x * 256 + (int)threadIdx.x) >> 6;
    int lane = threadIdx.x & 63;
    int r0 = wid * 2, r1 = r0 + 1;
    if (r0 >= n) return;
    uint2 i0 = row_info[r0];
    uint2 i1 = (r1 < n) ? row_info[r1] : make_uint2(0u, 0u);
    int p0 = (int)i0.y, p1 = (int)i1.y;
    if (p0 <= 32 && p1 <= 32) {
        int half = lane >> 5, hl = lane & 31;
        int base = half ? (int)i1.x : (int)i0.x;
        int pad  = half ? p1 : p0;
        int key = (hl < pad) ? csr_col[base + hl] : 0x7fffffff;
#pragma unroll
        for (int k = 2; k <= 32; k <<= 1) {
#pragma unroll
            for (int j = k >> 1; j > 0; j >>= 1) {
                int other = __shfl_xor(key, j, 64);  // j<32: stays in half
                bool takeMin = (((hl & j) == 0) == ((hl & k) == 0));
                int mn = min(key, other), mx = max(key, other);
                key = takeMin ? mn : mx;
            }
        }
        if (hl < pad) csr_col[base + hl] = key;
    } else {
        for (int t = 0; t < 2; t++) {
            int base = t ? (int)i1.x : (int)i0.x;
            int pad  = t ? p1 : p0;
            if (pad == 0) continue;
            if (pad <= 64) {
                int key = (lane < pad) ? csr_col[base + lane] : 0x7fffffff;
#pragma unroll
                for (int k = 2; k <= 64; k <<= 1) {
#pragma unroll
                    for (int j = k >> 1; j > 0; j >>= 1) {
                        int other = __shfl_xor(key, j, 64);
                        bool takeMin = (((lane & j) == 0) == ((lane & k) == 0));
                        int mn = min(key, other), mx = max(key, other);
                        key = takeMin ? mn : mx;
                    }
                }
                if (lane < pad) csr_col[base + lane] = key;
            } else if (lane == 0) {
                for (int i2 = 1; i2 < pad; i2++) {
                    int kk = csr_col[base + i2];
                    int j2 = i2 - 1;
                    while (j2 >= 0 && csr_col[base + j2] > kk) {
                        csr_col[base + j2 + 1] = csr_col[base + j2]; j2--;
                    }
                    csr_col[base + j2 + 1] = kk;
                }
            }
        }
    }
}

// One gather iteration: 16 UNCONDITIONAL uint2 gathers from cv0..cv3 + the
// NEXT iteration's 4 csr uint4 loads, all issued before a full scheduling
// barrier; accumulates predicated per 4-slot group (dead groups skip VALU via
// execz; guard slots would add zeros anyway). Groups 0,2 -> A accs; 1,3 -> B.
#define GATHER_ITER(cp, xs_in, ql, base, len)                               \
    uint2 u0 = xs_in[cv0.x * 16 + ql], u1 = xs_in[cv0.y * 16 + ql];         \
    uint2 u2 = xs_in[cv0.z * 16 + ql], u3 = xs_in[cv0.w * 16 + ql];         \
    uint2 u4 = xs_in[cv1.x * 16 + ql], u5 = xs_in[cv1.y * 16 + ql];         \
    uint2 u6 = xs_in[cv1.z * 16 + ql], u7 = xs_in[cv1.w * 16 + ql];         \
    uint2 u8 = xs_in[cv2.x * 16 + ql], u9 = xs_in[cv2.y * 16 + ql];         \
    uint2 u10 = xs_in[cv2.z * 16 + ql], u11 = xs_in[cv2.w * 16 + ql];       \
    uint2 u12 = xs_in[cv3.x * 16 + ql], u13 = xs_in[cv3.y * 16 + ql];       \
    uint2 u14 = xs_in[cv3.z * 16 + ql], u15 = xs_in[cv3.w * 16 + ql];       \
    {                                                                       \
        int nb4 = (base >> 2) + 4;                                          \
        nv0 = cp[nb4]; nv1 = cp[nb4 + 1];                                   \
        nv2 = cp[nb4 + 2]; nv3 = cp[nb4 + 3];                               \
    }                                                                       \
    __builtin_amdgcn_sched_barrier(0);                                      \
    if (base < len) {                                                       \
        acc2p(u0.x, hA01); acc2p(u0.y, hA23);                               \
        acc2p(u1.x, hA01); acc2p(u1.y, hA23);                               \
        acc2p(u2.x, hA01); acc2p(u2.y, hA23);                               \
        acc2p(u3.x, hA01); acc2p(u3.y, hA23);                               \
    }                                                                       \
    if (base + 4 < len) {                                                   \
        acc2p(u4.x, hB01); acc2p(u4.y, hB23);                               \
        acc2p(u5.x, hB01); acc2p(u5.y, hB23);                               \
        acc2p(u6.x, hB01); acc2p(u6.y, hB23);                               \
        acc2p(u7.x, hB01); acc2p(u7.y, hB23);                               \
    }                                                                       \
    if (base + 8 < len) {                                                   \
        acc2p(u8.x, hA01); acc2p(u8.y, hA23);                               \
        acc2p(u9.x, hA01); acc2p(u9.y, hA23);                               \
        acc2p(u10.x, hA01); acc2p(u10.y, hA23);                             \
        acc2p(u11.x, hA01); acc2p(u11.y, hA23);                             \
    }                                                                       \
    if (base + 12 < len) {                                                  \
        acc2p(u12.x, hB01); acc2p(u12.y, hB23);                             \
        acc2p(u13.x, hB01); acc2p(u13.y, hB23);                             \
        acc2p(u14.x, hB01); acc2p(u14.y, hB23);                             \
        acc2p(u15.x, hB01); acc2p(u15.y, hB23);                             \
    }                                                                       \
    cv0 = nv0; cv1 = nv1; cv2 = nv2; cv3 = nv3;

// Hop 1: xs1[r,:] = bf16( dis[r]^2 * ( xs0[r,:] + sum_c xs0[c,:] ) ).
// Wave w: rows from pinfo[4w..4w+3]; lane (q,ql) holds features 4ql..4ql+3.
__global__ __launch_bounds__(256, 5) void spmm_hop1_kernel(const uint2* __restrict__ xs_in,
                                                           uint2* __restrict__ xs_out,
                                                           const uint4* __restrict__ pinfo,
                                                           const int* __restrict__ csr_col,
                                                           int n) {
    int wave = (blockIdx.x * blockDim.x + threadIdx.x) >> 6;
    int lane = threadIdx.x & 63;
    int q = lane >> 4, ql = lane & 15;
    uint4 info = pinfo[wave * 4 + q];      // {csr base, padded len, row, dis}
    int s = (int)info.x, len = (int)info.y;
    int r = (int)info.z;
    bool valid = (r >= 0);
    int maxlen = len;
    maxlen = max(maxlen, __shfl_xor(maxlen, 16, 64));
    maxlen = max(maxlen, __shfl_xor(maxlen, 32, 64));

    v2f hA01 = {0.f, 0.f}, hA23 = {0.f, 0.f};
    v2f hB01 = {0.f, 0.f}, hB23 = {0.f, 0.f};
    const uint4* cp = (const uint4*)(csr_col + s);  // s is a multiple of 4
    uint4 cv0 = cp[0], cv1 = cp[1], cv2 = cp[2], cv3 = cp[3];
    uint4 nv0, nv1, nv2, nv3;
    for (int base = 0; base < maxlen; base += 16) {
        GATHER_ITER(cp, xs_in, ql, base, len)
    }
    if (valid) {
        v2f h01 = hA01 + hB01;
        v2f h23 = hA23 + hB23;
        uint2 us = xs_in[r * 16 + ql];  // self term
        acc2p(us.x, h01); acc2p(us.y, h23);
        float dr = __uint_as_float(info.w);
        float d2 = dr * dr;
        xs_out[r * 16 + ql] = make_uint2(pack_bf16_2(d2 * h01.x, d2 * h01.y),
                                         pack_bf16_2(d2 * h23.x, d2 * h23.y));
    }
}

// Hop 2 fused with logits + log_softmax. h2[r,:] = dis[r]*(xs1[r,:]+sum_c xs1[c,:]).
// GEMV: per-wave LDS transpose of h (hl, padded) + transposed padded Wt;
// lane ql covers classes ql, ql+16, (ql<8) ql+32. Inner loop is broadcast
// ds_read_b128 + FMA only (no shfl, no scalar W reads).
__global__ __launch_bounds__(256, 5) void spmm_logits_kernel(const uint2* __restrict__ xs_in,
                                                             const uint4* __restrict__ pinfo,
                                                             const int* __restrict__ csr_col,
                                                             const float* __restrict__ W,
                                                             const float* __restrict__ b,
                                                             float* __restrict__ out,
                                                             int n) {
    __shared__ float Wt[NCLS][D_FEAT + 4];  // transposed, padded: 2-lane/bank max
    __shared__ float bl[NCLS];
    __shared__ float hl[16][D_FEAT + 4];    // 4 waves x 4 rows; padded rows
    for (int i = threadIdx.x; i < D_FEAT * NCLS; i += 256) {
        int d = i / NCLS, cc = i - d * NCLS;
        Wt[cc][d] = W[i];
    }
    for (int i = threadIdx.x; i < NCLS; i += 256) bl[i] = b[i];
    __syncthreads();

    int wave = (blockIdx.x * blockDim.x + threadIdx.x) >> 6;
    int lane = threadIdx.x & 63;
    int q = lane >> 4, ql = lane & 15;
    uint4 info = pinfo[wave * 4 + q];      // {csr base, padded len, row, dis}
    int s = (int)info.x, len = (int)info.y;
    int r = (int)info.z;
    bool valid = (r >= 0);
    int maxlen = len;
    maxlen = max(maxlen, __shfl_xor(maxlen, 16, 64));
    maxlen = max(maxlen, __shfl_xor(maxlen, 32, 64));

    v2f hA01 = {0.f, 0.f}, hA23 = {0.f, 0.f};
    v2f hB01 = {0.f, 0.f}, hB23 = {0.f, 0.f};
    const uint4* cp = (const uint4*)(csr_col + s);
    uint4 cv0 = cp[0], cv1 = cp[1], cv2 = cp[2], cv3 = cp[3];
    uint4 nv0, nv1, nv2, nv3;
    for (int base = 0; base < maxlen; base += 16) {
        GATHER_ITER(cp, xs_in, ql, base, len)
    }

    float y0, y1, y2;
    int c0 = ql, c1 = ql + 16;
    int c2 = (ql < 8) ? (ql + 32) : ql;  // dup addr -> broadcast, no conflict
    {
        v2f h01 = hA01 + hB01;
        v2f h23 = hA23 + hB23;
        uint2 us = valid ? xs_in[r * 16 + ql] : make_uint2(0u, 0u);  // self term
        acc2p(us.x, h01); acc2p(us.y, h23);
        float dr = __uint_as_float(info.w);  // 0 for invalid slots
        float h0 = h01.x * dr, h1 = h01.y * dr, h2 = h23.x * dr, h3 = h23.y * dr;

        // per-wave transpose: same-wave produce->consume via LDS (lockstep;
        // compiler orders may-alias LDS ops) -- no barrier needed.
        int rowslot = ((threadIdx.x >> 6) << 2) + q;
        *(float4*)&hl[rowslot][ql * 4] = make_float4(h0, h1, h2, h3);

        y0 = bl[c0]; y1 = bl[c1]; y2 = bl[c2];
#pragma unroll
        for (int g = 0; g < 16; g++) {
            float4 hv = *(const float4*)&hl[rowslot][g * 4];   // quarter-broadcast
            float4 w0 = *(const float4*)&Wt[c0][g * 4];
            float4 w1 = *(const float4*)&Wt[c1][g * 4];
            float4 w2 = *(const float4*)&Wt[c2][g * 4];
            y0 += hv.x * w0.x + hv.y * w0.y + hv.z * w0.z + hv.w * w0.w;
            y1 += hv.x * w1.x + hv.y * w1.y + hv.z * w1.z + hv.w * w1.w;
            y2 += hv.x * w2.x + hv.y * w2.y + hv.z * w2.z + hv.w * w2.w;
        }
    }

    bool has3 = (ql < 8);
    float m = fmaxf(y0, y1);
    if (has3) m = fmaxf(m, y2);
#pragma unroll
    for (int o = 8; o > 0; o >>= 1) m = fmaxf(m, __shfl_xor(m, o, 64));
    float sm = __expf(y0 - m) + __expf(y1 - m) + (has3 ? __expf(y2 - m) : 0.f);
#pragma unroll
    for (int o = 8; o > 0; o >>= 1) sm += __shfl_xor(sm, o, 64);
    float lse = m + __logf(sm);

    if (valid) {
        float* op = out + (long long)r * NCLS;
        op[ql] = y0 - lse;
        op[ql + 16] = y1 - lse;
        if (has3) op[ql + 32] = y2 - lse;
    }
}

extern "C" void kernel_launch(void* const* d_in, const int* in_sizes, int n_in,
                              void* d_out, int out_size, void* d_ws, size_t ws_size,
                              hipStream_t stream) {
    const float* x  = (const float*)d_in[0];
    const int*   ei = (const int*)d_in[1];   // [2, E] flat: rows then cols (int32)
    const float* W  = (const float*)d_in[2]; // [64, 40]
    const float* b  = (const float*)d_in[3]; // [40]
    float* out = (float*)d_out;

    const int n = in_sizes[0] / D_FEAT;      // 100000
    const int e = in_sizes[1] / 2;           // 1600000
    const int nb = (n + BROWS - 1) / BROWS;  // 196

    const int* rows = ei;
    const int* cols = ei + e;

    // ws layout (int units, segments aligned):
    //   bucket_cursor | dis[n] | row_info[n] (uint2) | pinfo[nb*512] (uint4) |
    //   bins[nb*BINCAP] | csr_col[nb*CSRCAP] | xs0 | xs1       (~47 MB)
    size_t na = ((size_t)n + 256) & ~(size_t)255;
    size_t npm = (size_t)nb * BROWS;         // multiple of 512
    int*      bucket_cursor = (int*)d_ws;
    float*    dis           = (float*)(bucket_cursor + 256);
    uint2*    row_info      = (uint2*)(dis + na);
    uint4*    pinfo         = (uint4*)(row_info + na);
    unsigned* bins          = (unsigned*)(pinfo + npm);
    int*      csr_col       = (int*)(bins + (size_t)nb * BINCAP);
    unsigned* xs0           = (unsigned*)(csr_col + (size_t)nb * CSRCAP);
    unsigned* xs1           = xs0 + (size_t)(n + 1) * (D_FEAT / 2);

    const int BS = 256;

    hipMemsetAsync(bucket_cursor, 0, (size_t)nb * sizeof(int), stream);
    {
        int blocks = (e + BS * EPT - 1) / (BS * EPT);  // 250
        bin_edges_kernel<<<blocks, BS, 0, stream>>>(rows, cols, bucket_cursor, bins, e, nb);
    }
    build_csr_kernel<<<nb, 512, 0, stream>>>(bins, bucket_cursor, csr_col, row_info, dis,
                                             pinfo, n);
    {
        int nwv = (n + 1) / 2;                           // sort: 2 rows per wave
        int sortBlocks = (nwv * 64 + BS - 1) / BS;
        int tot = (n + 1) * (D_FEAT / 2);
        int scaleBlocks = (tot + BS - 1) / BS;
        sort_scale_kernel<<<sortBlocks + scaleBlocks, BS, 0, stream>>>(
            csr_col, row_info, x, dis, xs0, xs1, n, sortBlocks);
    }

    int nwaves = (int)npm / 4;               // 4 rows per wave
    int blocks = (nwaves * 64 + BS - 1) / BS;
    spmm_hop1_kernel<<<blocks, BS, 0, stream>>>((const uint2*)xs0, (uint2*)xs1, pinfo,
                                                csr_col, n);
    spmm_logits_kernel<<<blocks, BS, 0, stream>>>((const uint2*)xs1, pinfo, csr_col,
                                                  W, b, out, n);
}